// Round 1
// baseline (52.126 us; speedup 1.0000x reference)
//
#include <hip/hip_runtime.h>

typedef float v4f __attribute__((ext_vector_type(4)));

#define NATOM 128
#define FEAT 128
#define FILT 128
#define BATCH 8

// Kernel 1: s1[row,k] = sum_f sf[row,f] * W[f,k] + bias[k]
//           s2[row,k] = sum_f sf[row,f] * W[F+f,k]
// One block per row (b*N+n), 256 threads: tid = which*128 + k.
__global__ __launch_bounds__(256) void s_gemm_kernel(
    const float* __restrict__ sf, const float* __restrict__ W,
    const float* __restrict__ bias, float* __restrict__ s1,
    float* __restrict__ s2) {
  const int row = blockIdx.x;
  const int tid = threadIdx.x;
  const int k = tid & (FILT - 1);
  const int which = tid >> 7;  // 0 -> s1, 1 -> s2

  __shared__ float sfrow[FEAT];
  if (tid < FEAT) sfrow[tid] = sf[row * FEAT + tid];
  __syncthreads();

  const float* Wcol = W + which * FEAT * FILT + k;
  float acc = 0.f;
#pragma unroll
  for (int f = 0; f < FEAT; ++f) acc = fmaf(sfrow[f], Wcol[f * FILT], acc);

  if (which == 0)
    s1[row * FILT + k] = acc + bias[k];
  else
    s2[row * FILT + k] = acc;
}

// Kernel 2: out[b,i,j,c,k] = (s1[b,i,k] + s2[b,j,k]) * dist[b,i,j,c]
// One block per (b,i). 256 threads = 32 k-quads x 8 j-lanes.
// s1 row hoisted to registers; s2 rows are L2-resident (1 MB total, reused
// 128x each); output written with non-temporal float4 stores (never re-read).
__global__ __launch_bounds__(256) void expand_kernel(
    const float* __restrict__ s1, const float* __restrict__ s2,
    const float* __restrict__ dist, float* __restrict__ out) {
  const int bi = blockIdx.x;       // b*N + i
  const int b = bi >> 7;
  const int tid = threadIdx.x;
  const int kq = (tid & 31) << 2;  // k offset: 0..124 step 4
  const int jl = tid >> 5;         // 0..7

  const v4f s1v = *reinterpret_cast<const v4f*>(s1 + bi * FILT + kq);
  const float* s2base = s2 + (size_t)(b << 7) * FILT;
  const float* dbase = dist + (size_t)bi * NATOM * 3;
  float* obase = out + (size_t)bi * NATOM * 3 * FILT;

#pragma unroll 4
  for (int j0 = 0; j0 < NATOM; j0 += 8) {
    const int j = j0 + jl;
    const v4f s2v = *reinterpret_cast<const v4f*>(s2base + j * FILT + kq);
    const float d0 = dbase[j * 3 + 0];
    const float d1 = dbase[j * 3 + 1];
    const float d2 = dbase[j * 3 + 2];
    const v4f p = s1v + s2v;
    float* o = obase + (size_t)j * 3 * FILT + kq;
    __builtin_nontemporal_store(p * d0, reinterpret_cast<v4f*>(o));
    __builtin_nontemporal_store(p * d1, reinterpret_cast<v4f*>(o + FILT));
    __builtin_nontemporal_store(p * d2, reinterpret_cast<v4f*>(o + 2 * FILT));
  }
}

extern "C" void kernel_launch(void* const* d_in, const int* in_sizes, int n_in,
                              void* d_out, int out_size, void* d_ws, size_t ws_size,
                              hipStream_t stream) {
  const float* sf   = (const float*)d_in[0];  // (8,128,128)
  const float* dist = (const float*)d_in[1];  // (8,128,128,3)
  const float* W    = (const float*)d_in[2];  // (256,128)
  const float* bias = (const float*)d_in[3];  // (1,128)
  float* out = (float*)d_out;                 // (8,128,128,3,128)

  // workspace: s1 (1024*128 f32) + s2 (1024*128 f32) = 1 MiB
  float* s1 = (float*)d_ws;
  float* s2 = s1 + BATCH * NATOM * FILT;

  s_gemm_kernel<<<BATCH * NATOM, 256, 0, stream>>>(sf, W, bias, s1, s2);
  expand_kernel<<<BATCH * NATOM, 256, 0, stream>>>(s1, s2, dist, out);
}

// Round 2
// 48.941 us; speedup vs baseline: 1.0651x; 1.0651x over previous
//
#include <hip/hip_runtime.h>

typedef float v4f __attribute__((ext_vector_type(4)));

#define NATOM 128
#define FEAT 128
#define FILT 128
#define BATCH 8

// Kernel 1: s1[row,k] = sum_f sf[row,f] * W[f,k] + bias[k]
//           s2[row,k] = sum_f sf[row,f] * W[F+f,k]
// One block per row (b*N+n), 256 threads: tid = which*128 + k.
__global__ __launch_bounds__(256) void s_gemm_kernel(
    const float* __restrict__ sf, const float* __restrict__ W,
    const float* __restrict__ bias, float* __restrict__ s1,
    float* __restrict__ s2) {
  const int row = blockIdx.x;
  const int tid = threadIdx.x;
  const int k = tid & (FILT - 1);
  const int which = tid >> 7;  // 0 -> s1, 1 -> s2

  __shared__ float sfrow[FEAT];
  if (tid < FEAT) sfrow[tid] = sf[row * FEAT + tid];
  __syncthreads();

  const float* Wcol = W + which * FEAT * FILT + k;
  float acc = 0.f;
#pragma unroll
  for (int f = 0; f < FEAT; ++f) acc = fmaf(sfrow[f], Wcol[f * FILT], acc);

  if (which == 0)
    s1[row * FILT + k] = acc + bias[k];
  else
    s2[row * FILT + k] = acc;
}

// Kernel 2: out[b,i,j,c,k] = (s1[b,i,k] + s2[b,j,k]) * dist[b,i,j,c]
// One block per (b,i,j-half): 2048 blocks for TLP. 256 threads =
// 8 j-lanes x 32 k-quads. dist row staged in LDS (removes global loads from
// the inner loop); j-loop fully unrolled -> 8 independent s2 loads in flight;
// non-temporal stores (output never re-read, keep L2 for s2/dist).
__global__ __launch_bounds__(256) void expand_kernel(
    const float* __restrict__ s1, const float* __restrict__ s2,
    const float* __restrict__ dist, float* __restrict__ out) {
  const int blk = blockIdx.x;
  const int bi = blk >> 1;         // b*N + i
  const int jh = blk & 1;          // which half of j
  const int b = bi >> 7;
  const int tid = threadIdx.x;
  const int kq = (tid & 31) << 2;  // k offset: 0..124 step 4
  const int jl = tid >> 5;         // 0..7

  // Stage this block's dist slice: 64 j x 3 c = 192 floats.
  __shared__ float dl[64 * 3];
  const float* dbase = dist + (size_t)bi * NATOM * 3 + jh * 64 * 3;
  if (tid < 192) dl[tid] = dbase[tid];

  const v4f s1v = *reinterpret_cast<const v4f*>(s1 + bi * FILT + kq);
  const float* s2base = s2 + ((size_t)(b << 7) + jh * 64) * FILT;
  float* obase = out + ((size_t)bi * NATOM + jh * 64) * 3 * FILT;

  __syncthreads();

#pragma unroll
  for (int j0 = 0; j0 < 64; j0 += 8) {
    const int jloc = j0 + jl;
    const v4f s2v = *reinterpret_cast<const v4f*>(s2base + jloc * FILT + kq);
    const float d0 = dl[jloc * 3 + 0];
    const float d1 = dl[jloc * 3 + 1];
    const float d2 = dl[jloc * 3 + 2];
    const v4f p = s1v + s2v;
    float* o = obase + (size_t)jloc * 3 * FILT + kq;
    __builtin_nontemporal_store(p * d0, reinterpret_cast<v4f*>(o));
    __builtin_nontemporal_store(p * d1, reinterpret_cast<v4f*>(o + FILT));
    __builtin_nontemporal_store(p * d2, reinterpret_cast<v4f*>(o + 2 * FILT));
  }
}

extern "C" void kernel_launch(void* const* d_in, const int* in_sizes, int n_in,
                              void* d_out, int out_size, void* d_ws, size_t ws_size,
                              hipStream_t stream) {
  const float* sf   = (const float*)d_in[0];  // (8,128,128)
  const float* dist = (const float*)d_in[1];  // (8,128,128,3)
  const float* W    = (const float*)d_in[2];  // (256,128)
  const float* bias = (const float*)d_in[3];  // (1,128)
  float* out = (float*)d_out;                 // (8,128,128,3,128)

  // workspace: s1 (1024*128 f32) + s2 (1024*128 f32) = 1 MiB
  float* s1 = (float*)d_ws;
  float* s2 = s1 + BATCH * NATOM * FILT;

  s_gemm_kernel<<<BATCH * NATOM, 256, 0, stream>>>(sf, W, bias, s1, s2);
  expand_kernel<<<BATCH * NATOM * 2, 256, 0, stream>>>(s1, s2, dist, out);
}

// Round 3
// 42.758 us; speedup vs baseline: 1.2191x; 1.1446x over previous
//
#include <hip/hip_runtime.h>

typedef float v4f __attribute__((ext_vector_type(4)));

#define NATOM 128
#define FEAT 128
#define FILT 128
#define BATCH 8

// Kernel 1: s1[row,k] = sum_f sf[row,f] * W[f,k] + bias[k]
//           s2[row,k] = sum_f sf[row,f] * W[F+f,k]
// One block per row (b*N+n), 256 threads: tid = which*128 + k.
__global__ __launch_bounds__(256) void s_gemm_kernel(
    const float* __restrict__ sf, const float* __restrict__ W,
    const float* __restrict__ bias, float* __restrict__ s1,
    float* __restrict__ s2) {
  const int row = blockIdx.x;
  const int tid = threadIdx.x;
  const int k = tid & (FILT - 1);
  const int which = tid >> 7;  // 0 -> s1, 1 -> s2

  __shared__ float sfrow[FEAT];
  if (tid < FEAT) sfrow[tid] = sf[row * FEAT + tid];
  __syncthreads();

  const float* Wcol = W + which * FEAT * FILT + k;
  float acc = 0.f;
#pragma unroll
  for (int f = 0; f < FEAT; ++f) acc = fmaf(sfrow[f], Wcol[f * FILT], acc);

  if (which == 0)
    s1[row * FILT + k] = acc + bias[k];
  else
    s2[row * FILT + k] = acc;
}

// Kernel 2: out[b,i,j,c,k] = (s1[b,i,k] + s2[b,j,k]) * dist[b,i,j,c]
// One block per (b,i,j-half): 2048 blocks. 256 threads = 8 j-lanes x 32
// k-quads. dist staged in LDS; j-loop fully unrolled. R2->R3 single change:
// plain stores instead of non-temporal (fill kernel shows plain stores
// sustain 6.9 TB/s; nt bypasses L2 write-aggregation).
__global__ __launch_bounds__(256) void expand_kernel(
    const float* __restrict__ s1, const float* __restrict__ s2,
    const float* __restrict__ dist, float* __restrict__ out) {
  const int blk = blockIdx.x;
  const int bi = blk >> 1;         // b*N + i
  const int jh = blk & 1;          // which half of j
  const int b = bi >> 7;
  const int tid = threadIdx.x;
  const int kq = (tid & 31) << 2;  // k offset: 0..124 step 4
  const int jl = tid >> 5;         // 0..7

  // Stage this block's dist slice: 64 j x 3 c = 192 floats.
  __shared__ float dl[64 * 3];
  const float* dbase = dist + (size_t)bi * NATOM * 3 + jh * 64 * 3;
  if (tid < 192) dl[tid] = dbase[tid];

  const v4f s1v = *reinterpret_cast<const v4f*>(s1 + bi * FILT + kq);
  const float* s2base = s2 + ((size_t)(b << 7) + jh * 64) * FILT;
  float* obase = out + ((size_t)bi * NATOM + jh * 64) * 3 * FILT;

  __syncthreads();

#pragma unroll
  for (int j0 = 0; j0 < 64; j0 += 8) {
    const int jloc = j0 + jl;
    const v4f s2v = *reinterpret_cast<const v4f*>(s2base + jloc * FILT + kq);
    const float d0 = dl[jloc * 3 + 0];
    const float d1 = dl[jloc * 3 + 1];
    const float d2 = dl[jloc * 3 + 2];
    const v4f p = s1v + s2v;
    float* o = obase + (size_t)jloc * 3 * FILT + kq;
    *reinterpret_cast<v4f*>(o) = p * d0;
    *reinterpret_cast<v4f*>(o + FILT) = p * d1;
    *reinterpret_cast<v4f*>(o + 2 * FILT) = p * d2;
  }
}

extern "C" void kernel_launch(void* const* d_in, const int* in_sizes, int n_in,
                              void* d_out, int out_size, void* d_ws, size_t ws_size,
                              hipStream_t stream) {
  const float* sf   = (const float*)d_in[0];  // (8,128,128)
  const float* dist = (const float*)d_in[1];  // (8,128,128,3)
  const float* W    = (const float*)d_in[2];  // (256,128)
  const float* bias = (const float*)d_in[3];  // (1,128)
  float* out = (float*)d_out;                 // (8,128,128,3,128)

  // workspace: s1 (1024*128 f32) + s2 (1024*128 f32) = 1 MiB
  float* s1 = (float*)d_ws;
  float* s2 = s1 + BATCH * NATOM * FILT;

  s_gemm_kernel<<<BATCH * NATOM, 256, 0, stream>>>(sf, W, bias, s1, s2);
  expand_kernel<<<BATCH * NATOM * 2, 256, 0, stream>>>(s1, s2, dist, out);
}